// Round 7
// baseline (135.088 us; speedup 1.0000x reference)
//
#include <hip/hip_runtime.h>
#include <math.h>

#define BB 8
#define TQ 256
#define TV 512
#define DD 128
#define LN_EPS 1e-3f

typedef float f2 __attribute__((ext_vector_type(2)));
typedef float f4 __attribute__((ext_vector_type(4)));

static __device__ __forceinline__ f2 fma2s(f2 a, float s, f2 c) {
    f2 r; r[0] = fmaf(a[0], s, c[0]); r[1] = fmaf(a[1], s, c[1]); return r;
}
static __device__ __forceinline__ f2 fma2v(f2 a, f2 b, f2 c) {
    f2 r; r[0] = fmaf(a[0], b[0], c[0]); r[1] = fmaf(a[1], b[1], c[1]); return r;
}
static __device__ __forceinline__ f2 rcp2(f2 a) {
    f2 r; r[0] = __builtin_amdgcn_rcpf(a[0]); r[1] = __builtin_amdgcn_rcpf(a[1]); return r;
}

// ---- prep: FT2[b][g][j][dg] = exp(2*ctx[b][j][g*16+dg]), g=d/16, dg=d%16 ----
// Per-thread-contiguous 64B chunks so attn's 4 b128 loads per g are L1-local.
__global__ __launch_bounds__(256) void prep_kernel(const float* __restrict__ ctx,
                                                   float* __restrict__ ws) {
    int idx = blockIdx.x * 256 + threadIdx.x;      // f4 index over [b][j][d4]
    int d4 = idx & 31, j = (idx >> 5) & 511, b = idx >> 14;
    f4 c = ((const f4*)ctx)[idx];
    f4 e;
#pragma unroll
    for (int i = 0; i < 4; ++i) e[i] = __expf(2.0f * c[i]);
    int g = d4 >> 2, q = d4 & 3;
    ((f4*)ws)[(((b * 8 + g) * 512) + j) * 4 + q] = e;
}

// ---- attn: 512 thr (8 waves), TI=2 rows, grid 1024 -> 4 blocks/CU ----------
// score'[j] = sum_d (-2 s_d)/(1 + E[i,d]*F[j,d]);  pair-merged reciprocals.
// Thread t owns j = t (full 128 d, both rows). NO register arrays (rule #20).
__global__ __launch_bounds__(512, 8) void attn_kernel(const float* __restrict__ x,
                                                      const float* __restrict__ ctx,
                                                      const float* __restrict__ scale,
                                                      const float* __restrict__ gamma,
                                                      const float* __restrict__ beta,
                                                      const float* __restrict__ ws,
                                                      float* __restrict__ out) {
    __shared__ f2    E2[DD];          // [d] -> e^{2x} for 2 rows      1KB
    __shared__ f4    sn4[DD / 4];     // -2*scale by d-quad            0.5KB
    __shared__ f2    wT[TV];          // softmax weights               4KB
    __shared__ float red[8][2][DD];   // PV partials [g][r][d]         8KB
    __shared__ f2    mred[8], sred[8];
    __shared__ float lnred[4][2];

    const int t  = threadIdx.x;
    const int bg = blockIdx.x;
    // bijective XCD swizzle: 1024 blocks, XCD k owns batch k (ctx+F L2-resident)
    const int wg   = (bg & 7) * 128 + (bg >> 3);
    const int b    = wg >> 7;
    const int i0   = (wg & 127) * 2;
    const int wv   = t >> 6;
    const int lane = t & 63;

    // ---- setup: E rows + sn ----
    if (t < DD) {
        float v0 = x[(size_t)(b * TQ + i0) * DD + t];
        float v1 = x[(size_t)(b * TQ + i0 + 1) * DD + t];
        f2 e; e[0] = __expf(2.0f * v0); e[1] = __expf(2.0f * v1);
        E2[t] = e;
    } else if (t < DD + DD / 4) {
        f4 s = ((const f4*)scale)[t - DD];
        f4 o; o[0] = -2.f * s[0]; o[1] = -2.f * s[1]; o[2] = -2.f * s[2]; o[3] = -2.f * s[3];
        sn4[t - DD] = o;
    }
    __syncthreads();

    // ---- phase 1: scores ----
    const int j = t;
    const f2 one2 = {1.f, 1.f};
    f2 acc = {0.f, 0.f};

    // consume one F quad immediately; named temps only (no indexed reg arrays)
    auto proc = [&](f4 Fq, int db0, f4 sn) {
        f2 Ea = E2[db0 + 0], Eb = E2[db0 + 1], Ec = E2[db0 + 2], Ed = E2[db0 + 3];
        // pair (d0,d1): sn0/da + sn1/db = (sn0*db + sn1*da)/(da*db)
        f2 da = fma2s(Ea, Fq[0], one2);
        f2 db = fma2s(Eb, Fq[1], one2);
        f2 nu = db * sn[0];
        nu = fma2s(da, sn[1], nu);
        acc = fma2v(nu, rcp2(da * db), acc);
        // pair (d2,d3)
        f2 dc = fma2s(Ec, Fq[2], one2);
        f2 de = fma2s(Ed, Fq[3], one2);
        f2 n2 = de * sn[2];
        n2 = fma2s(dc, sn[3], n2);
        acc = fma2v(n2, rcp2(dc * de), acc);
    };

    {
        const f4* Fp = (const f4*)ws + (size_t)b * 16384 + j * 4;
#pragma unroll 2
        for (int g = 0; g < 8; ++g) {
            f4 F0 = Fp[0];
            f4 F1 = Fp[1];
            f4 F2v = Fp[2];
            f4 F3 = Fp[3];
            Fp += 2048;
            f4 s0 = sn4[g * 4 + 0], s1 = sn4[g * 4 + 1];
            f4 s2 = sn4[g * 4 + 2], s3 = sn4[g * 4 + 3];
            proc(F0, g * 16 + 0,  s0);
            proc(F1, g * 16 + 4,  s1);
            proc(F2v, g * 16 + 8, s2);
            proc(F3, g * 16 + 12, s3);
        }
    }

    // ---- phase 2: softmax over 512 j, single-barrier (m,s) combine ----
    f2 m = acc;
#pragma unroll
    for (int off = 32; off > 0; off >>= 1) {
        m[0] = fmaxf(m[0], __shfl_xor(m[0], off));
        m[1] = fmaxf(m[1], __shfl_xor(m[1], off));
    }
    f2 e;
    e[0] = __expf(acc[0] - m[0]);
    e[1] = __expf(acc[1] - m[1]);
    f2 s = e;
#pragma unroll
    for (int off = 32; off > 0; off >>= 1) {
        s[0] += __shfl_xor(s[0], off);
        s[1] += __shfl_xor(s[1], off);
    }
    if (lane == 0) { mred[wv] = m; sred[wv] = s; }
    __syncthreads();
    {
        f2 M = mred[0];
#pragma unroll
        for (int w = 1; w < 8; ++w) {
            f2 o = mred[w];
            M[0] = fmaxf(M[0], o[0]); M[1] = fmaxf(M[1], o[1]);
        }
        f2 S = {0.f, 0.f};
#pragma unroll
        for (int w = 0; w < 8; ++w) {
            f2 mw = mred[w], sw = sred[w];
            S[0] += sw[0] * __expf(mw[0] - M[0]);
            S[1] += sw[1] * __expf(mw[1] - M[1]);
        }
        f2 w2;
        w2[0] = __expf(acc[0] - M[0]) * __builtin_amdgcn_rcpf(S[0]);
        w2[1] = __expf(acc[1] - M[1]) * __builtin_amdgcn_rcpf(S[1]);
        wT[j] = w2;
    }
    __syncthreads();

    // ---- phase 3: attn_out[r][d] = sum_j w[r][j]*ctx[j][d]; 8 j-groups x 64 ----
    {
        const int g  = t >> 6;         // 0..7
        const int d2 = t & 63;         // d-pair
        const f2* cp = (const f2*)ctx + (size_t)(b * TV + g * 64) * 64 + d2;
        f4 p = {0.f, 0.f, 0.f, 0.f};
#pragma unroll 4
        for (int js = 0; js < 64; ++js) {
            f2 wj = wT[g * 64 + js];          // LDS broadcast
            f2 cv = cp[(size_t)js * 64];      // coalesced 512B/instr
            p[0] = fmaf(wj[0], cv[0], p[0]);
            p[1] = fmaf(wj[0], cv[1], p[1]);
            p[2] = fmaf(wj[1], cv[0], p[2]);
            p[3] = fmaf(wj[1], cv[1], p[3]);
        }
        *(f2*)&red[g][0][2 * d2] = f2{p[0], p[1]};
        *(f2*)&red[g][1][2 * d2] = f2{p[2], p[3]};
    }
    __syncthreads();

    // ---- phase 4: reduce, residual, LayerNorm, store (t<256) ----
    float y = 0.f;
    const int r = t >> 7, dd = t & 127;
    if (t < 256) {
        float attn = 0.f;
#pragma unroll
        for (int g2 = 0; g2 < 8; ++g2) attn += red[g2][r][dd];
        y = x[(size_t)(b * TQ + i0 + r) * DD + dd] + attn;
    }
    float s1 = y, s2 = y * y;
#pragma unroll
    for (int off = 32; off > 0; off >>= 1) {
        s1 += __shfl_xor(s1, off);
        s2 += __shfl_xor(s2, off);
    }
    if (t < 256 && lane == 0) { lnred[wv][0] = s1; lnred[wv][1] = s2; }
    __syncthreads();
    if (t < 256) {
        float S1 = lnred[2 * r][0] + lnred[2 * r + 1][0];
        float S2 = lnred[2 * r][1] + lnred[2 * r + 1][1];
        float mu  = S1 * (1.0f / 128.0f);
        float var = S2 * (1.0f / 128.0f) - mu * mu;
        float inv = rsqrtf(var + LN_EPS);
        out[(size_t)(b * TQ + i0 + r) * DD + dd] = gamma[dd] * (y - mu) * inv + beta[dd];
    }
}

extern "C" void kernel_launch(void* const* d_in, const int* in_sizes, int n_in,
                              void* d_out, int out_size, void* d_ws, size_t ws_size,
                              hipStream_t stream) {
    const float* x     = (const float*)d_in[0];
    const float* ctx   = (const float*)d_in[1];
    const float* scale = (const float*)d_in[2];
    const float* gamma = (const float*)d_in[3];
    const float* beta  = (const float*)d_in[4];
    float* out = (float*)d_out;
    float* ws  = (float*)d_ws;     // FT2: 2MB

    prep_kernel<<<512, 256, 0, stream>>>(ctx, ws);
    attn_kernel<<<1024, 512, 0, stream>>>(x, ctx, scale, gamma, beta, ws, out);
}

// Round 12
// 100.562 us; speedup vs baseline: 1.3433x; 1.3433x over previous
//
#include <hip/hip_runtime.h>
#include <math.h>

#define BB 8
#define TQ 256
#define TV 512
#define DD 128
#define LN_EPS 1e-3f

typedef float f2 __attribute__((ext_vector_type(2)));
typedef float f4 __attribute__((ext_vector_type(4)));

static __device__ __forceinline__ f2 fma2s(f2 a, float s, f2 c) {
    f2 r; r[0] = fmaf(a[0], s, c[0]); r[1] = fmaf(a[1], s, c[1]); return r;
}
static __device__ __forceinline__ f2 fma2v(f2 a, f2 b, f2 c) {
    f2 r; r[0] = fmaf(a[0], b[0], c[0]); r[1] = fmaf(a[1], b[1], c[1]); return r;
}
static __device__ __forceinline__ f2 rcp2(f2 a) {
    f2 r; r[0] = __builtin_amdgcn_rcpf(a[0]); r[1] = __builtin_amdgcn_rcpf(a[1]); return r;
}

// ---- prep: FT2[b][g][j][dg] = exp(2*ctx[b][j][g*16+dg]), g=d/16, dg=d%16 ----
__global__ __launch_bounds__(256) void prep_kernel(const float* __restrict__ ctx,
                                                   float* __restrict__ ws) {
    int idx = blockIdx.x * 256 + threadIdx.x;      // f4 index over [b][j][d4]
    int d4 = idx & 31, j = (idx >> 5) & 511, b = idx >> 14;
    f4 c = ((const f4*)ctx)[idx];
    f4 e;
#pragma unroll
    for (int i = 0; i < 4; ++i) e[i] = __expf(2.0f * c[i]);
    int g = d4 >> 2, q = d4 & 3;
    ((f4*)ws)[(((b * 8 + g) * 512) + j) * 4 + q] = e;
}

// ---- attn: 512 thr (8 waves), TI=2 rows, grid 1024 ------------------------
// score'[j] = sum_d (-2 s_d)/(1 + E[i,d]*F[j,d]);  pair-merged reciprocals.
// NO min-waves launch bound: let the allocator avoid spill (R7 post-mortem).
__global__ __launch_bounds__(512) void attn_kernel(const float* __restrict__ x,
                                                   const float* __restrict__ ctx,
                                                   const float* __restrict__ scale,
                                                   const float* __restrict__ gamma,
                                                   const float* __restrict__ beta,
                                                   const float* __restrict__ ws,
                                                   float* __restrict__ out) {
    __shared__ f2    E2[DD];          // [d] -> e^{2x} for 2 rows      1KB
    __shared__ f4    sn4[DD / 4];     // -2*scale by d-quad            0.5KB
    __shared__ f2    wT[TV];          // softmax weights               4KB
    __shared__ float red[8][2][DD];   // PV partials [g][r][d]         8KB
    __shared__ f2    mred[8], sred[8];
    __shared__ float lnred[4][2];

    const int t  = threadIdx.x;
    const int bg = blockIdx.x;
    // bijective XCD swizzle: 1024 blocks, XCD k owns batch k (ctx+F L2-resident)
    const int wg   = (bg & 7) * 128 + (bg >> 3);
    const int b    = wg >> 7;
    const int i0   = (wg & 127) * 2;
    const int wv   = t >> 6;
    const int lane = t & 63;

    // ---- setup: E rows + sn ----
    if (t < DD) {
        float v0 = x[(size_t)(b * TQ + i0) * DD + t];
        float v1 = x[(size_t)(b * TQ + i0 + 1) * DD + t];
        f2 e; e[0] = __expf(2.0f * v0); e[1] = __expf(2.0f * v1);
        E2[t] = e;
    } else if (t < DD + DD / 4) {
        f4 s = ((const f4*)scale)[t - DD];
        f4 o; o[0] = -2.f * s[0]; o[1] = -2.f * s[1]; o[2] = -2.f * s[2]; o[3] = -2.f * s[3];
        sn4[t - DD] = o;
    }
    __syncthreads();

    // ---- phase 1: scores ----
    const int j = t;
    const f2 one2 = {1.f, 1.f};
    f2 acc = {0.f, 0.f};

    auto proc = [&](f4 Fq, int db0, f4 sn) {
        f2 Ea = E2[db0 + 0], Eb = E2[db0 + 1], Ec = E2[db0 + 2], Ed = E2[db0 + 3];
        // pair (d0,d1): sn0/da + sn1/db = (sn0*db + sn1*da)/(da*db)
        f2 da = fma2s(Ea, Fq[0], one2);
        f2 db = fma2s(Eb, Fq[1], one2);
        f2 nu = db * sn[0];
        nu = fma2s(da, sn[1], nu);
        acc = fma2v(nu, rcp2(da * db), acc);
        // pair (d2,d3)
        f2 dc = fma2s(Ec, Fq[2], one2);
        f2 de = fma2s(Ed, Fq[3], one2);
        f2 n2 = de * sn[2];
        n2 = fma2s(dc, sn[3], n2);
        acc = fma2v(n2, rcp2(dc * de), acc);
    };

    {
        const f4* Fp = (const f4*)ws + (size_t)b * 16384 + j * 4;
        for (int g = 0; g < 8; ++g) {
            f4 F0 = Fp[0];
            f4 F1 = Fp[1];
            f4 F2v = Fp[2];
            f4 F3 = Fp[3];
            Fp += 2048;
            f4 s0 = sn4[g * 4 + 0], s1 = sn4[g * 4 + 1];
            f4 s2 = sn4[g * 4 + 2], s3 = sn4[g * 4 + 3];
            proc(F0, g * 16 + 0,  s0);
            proc(F1, g * 16 + 4,  s1);
            proc(F2v, g * 16 + 8, s2);
            proc(F3, g * 16 + 12, s3);
        }
    }

    // ---- phase 2: softmax over 512 j, single-barrier (m,s) combine ----
    f2 m = acc;
#pragma unroll
    for (int off = 32; off > 0; off >>= 1) {
        m[0] = fmaxf(m[0], __shfl_xor(m[0], off));
        m[1] = fmaxf(m[1], __shfl_xor(m[1], off));
    }
    f2 e;
    e[0] = __expf(acc[0] - m[0]);
    e[1] = __expf(acc[1] - m[1]);
    f2 s = e;
#pragma unroll
    for (int off = 32; off > 0; off >>= 1) {
        s[0] += __shfl_xor(s[0], off);
        s[1] += __shfl_xor(s[1], off);
    }
    if (lane == 0) { mred[wv] = m; sred[wv] = s; }
    __syncthreads();
    {
        f2 M = mred[0];
#pragma unroll
        for (int w = 1; w < 8; ++w) {
            f2 o = mred[w];
            M[0] = fmaxf(M[0], o[0]); M[1] = fmaxf(M[1], o[1]);
        }
        f2 S = {0.f, 0.f};
#pragma unroll
        for (int w = 0; w < 8; ++w) {
            f2 mw = mred[w], sw = sred[w];
            S[0] += sw[0] * __expf(mw[0] - M[0]);
            S[1] += sw[1] * __expf(mw[1] - M[1]);
        }
        f2 w2;
        w2[0] = __expf(acc[0] - M[0]) * __builtin_amdgcn_rcpf(S[0]);
        w2[1] = __expf(acc[1] - M[1]) * __builtin_amdgcn_rcpf(S[1]);
        wT[j] = w2;
    }
    __syncthreads();

    // ---- phase 3: attn_out[r][d] = sum_j w[r][j]*ctx[j][d]; 8 j-groups x 64 ----
    {
        const int g  = t >> 6;         // 0..7
        const int d2 = t & 63;         // d-pair
        const f2* cp = (const f2*)ctx + (size_t)(b * TV + g * 64) * 64 + d2;
        f4 p = {0.f, 0.f, 0.f, 0.f};
#pragma unroll 4
        for (int js = 0; js < 64; ++js) {
            f2 wj = wT[g * 64 + js];          // LDS broadcast
            f2 cv = cp[(size_t)js * 64];      // coalesced 512B/instr
            p[0] = fmaf(wj[0], cv[0], p[0]);
            p[1] = fmaf(wj[0], cv[1], p[1]);
            p[2] = fmaf(wj[1], cv[0], p[2]);
            p[3] = fmaf(wj[1], cv[1], p[3]);
        }
        *(f2*)&red[g][0][2 * d2] = f2{p[0], p[1]};
        *(f2*)&red[g][1][2 * d2] = f2{p[2], p[3]};
    }
    __syncthreads();

    // ---- phase 4: reduce, residual, LayerNorm, store (t<256) ----
    float y = 0.f;
    const int r = t >> 7, dd = t & 127;
    if (t < 256) {
        float attn = 0.f;
#pragma unroll
        for (int g2 = 0; g2 < 8; ++g2) attn += red[g2][r][dd];
        y = x[(size_t)(b * TQ + i0 + r) * DD + dd] + attn;
    }
    float s1 = y, s2 = y * y;
#pragma unroll
    for (int off = 32; off > 0; off >>= 1) {
        s1 += __shfl_xor(s1, off);
        s2 += __shfl_xor(s2, off);
    }
    if (t < 256 && lane == 0) { lnred[wv][0] = s1; lnred[wv][1] = s2; }
    __syncthreads();
    if (t < 256) {
        float S1 = lnred[2 * r][0] + lnred[2 * r + 1][0];
        float S2 = lnred[2 * r][1] + lnred[2 * r + 1][1];
        float mu  = S1 * (1.0f / 128.0f);
        float var = S2 * (1.0f / 128.0f) - mu * mu;
        float inv = rsqrtf(var + LN_EPS);
        out[(size_t)(b * TQ + i0 + r) * DD + dd] = gamma[dd] * (y - mu) * inv + beta[dd];
    }
}

extern "C" void kernel_launch(void* const* d_in, const int* in_sizes, int n_in,
                              void* d_out, int out_size, void* d_ws, size_t ws_size,
                              hipStream_t stream) {
    const float* x     = (const float*)d_in[0];
    const float* ctx   = (const float*)d_in[1];
    const float* scale = (const float*)d_in[2];
    const float* gamma = (const float*)d_in[3];
    const float* beta  = (const float*)d_in[4];
    float* out = (float*)d_out;
    float* ws  = (float*)d_ws;     // FT2: 2MB

    prep_kernel<<<512, 256, 0, stream>>>(ctx, ws);
    attn_kernel<<<1024, 512, 0, stream>>>(x, ctx, scale, gamma, beta, ws, out);
}